// Round 5
// baseline (543.410 us; speedup 1.0000x reference)
//
#include <hip/hip_runtime.h>
#include <hip/hip_cooperative_groups.h>
#include <hip/hip_bf16.h>
#include <math.h>

namespace cg = cooperative_groups;

#define BB 4
#define NN 768
#define MM 768
#define CC 128
#define KK 16
#define KK1 8
#define NKP 256

// output offsets (floats)
#define OFF_R    0
#define OFF_T    36
#define OFF_SK   48
#define OFF_TK   3120
#define OFF_SKK  6192
#define OFF_TKK  55344
#define OFF_LOSS 104496

// ============================ MEGA (cooperative) ============================
__global__ __launch_bounds__(256, 2)
void mega_k(const float* __restrict__ src, const float* __restrict__ tgt,
            const float* __restrict__ se, const float* __restrict__ te,
            const int* __restrict__ src_idx, const float* __restrict__ src_knn,
            const int* __restrict__ src_idx1, const int* __restrict__ idx2,
            const float* __restrict__ w1, const float* __restrict__ b1,
            const float* __restrict__ w2, const float* __restrict__ b2,
            const float* __restrict__ w3, const float* __restrict__ b3,
            const float* __restrict__ w4, const float* __restrict__ b4,
            const float* __restrict__ nn_margin_p, float* __restrict__ out,
            float* __restrict__ dist, float* __restrict__ scores,
            float* __restrict__ src_corr, float* __restrict__ mmax,
            float* __restrict__ knnD, float* __restrict__ wgt,
            float* __restrict__ Rws, float* __restrict__ tws,
            int* __restrict__ topk, float* __restrict__ lossAcc) {
    cg::grid_group grid = cg::this_grid();
    __shared__ __attribute__((aligned(16))) char smem_raw[66560];
    float* smem = (float*)smem_raw;
    int tid = threadIdx.x;
    int lane = tid & 63, wv = tid >> 6;
    int nblk = (int)gridDim.x;

    // -------- P1: dist = xx+yy-2*x.y  (64x64 tiles, 4x4/thread) --------
    {
        float* xt = smem;           // 8192 floats
        float* yt = smem + 8192;    // 8192
        float* nx = smem + 16384;   // 64
        float* ny = smem + 16448;   // 64
        for (int job = blockIdx.x; job < 576; job += nblk) {
            __syncthreads();
            int b = job / 144, rem = job % 144;
            int n0 = (rem / 12) * 64, m0 = (rem % 12) * 64;
            for (int i = tid; i < CC * 16; i += 256) {
                int c = i >> 4, v = i & 15;
                ((float4*)xt)[c * 16 + v] = ((const float4*)(se + (size_t)(b * CC + c) * NN + n0))[v];
                ((float4*)yt)[c * 16 + v] = ((const float4*)(te + (size_t)(b * CC + c) * MM + m0))[v];
            }
            __syncthreads();
            if (tid < 64) {
                float s = 0.f;
                for (int c = 0; c < CC; c++) { float v = xt[c * 64 + tid]; s += v * v; }
                nx[tid] = s;
            } else if (tid < 128) {
                int v0 = tid - 64;
                float s = 0.f;
                for (int c = 0; c < CC; c++) { float v = yt[c * 64 + v0]; s += v * v; }
                ny[v0] = s;
            }
            int mi = (tid & 15) * 4, ni = (tid >> 4) * 4;
            float acc[16];
            for (int k = 0; k < 16; k++) acc[k] = 0.f;
            for (int c = 0; c < CC; c++) {
                float4 xv = *(const float4*)&xt[c * 64 + ni];
                float4 yv = *(const float4*)&yt[c * 64 + mi];
                acc[0]  += xv.x * yv.x; acc[1]  += xv.x * yv.y; acc[2]  += xv.x * yv.z; acc[3]  += xv.x * yv.w;
                acc[4]  += xv.y * yv.x; acc[5]  += xv.y * yv.y; acc[6]  += xv.y * yv.z; acc[7]  += xv.y * yv.w;
                acc[8]  += xv.z * yv.x; acc[9]  += xv.z * yv.y; acc[10] += xv.z * yv.z; acc[11] += xv.z * yv.w;
                acc[12] += xv.w * yv.x; acc[13] += xv.w * yv.y; acc[14] += xv.w * yv.z; acc[15] += xv.w * yv.w;
            }
            __syncthreads();
            float ny0 = ny[mi], ny1 = ny[mi + 1], ny2 = ny[mi + 2], ny3 = ny[mi + 3];
            for (int i = 0; i < 4; i++) {
                float nxi = nx[ni + i];
                float4 o;
                o.x = nxi + ny0 - 2.f * acc[i * 4 + 0];
                o.y = nxi + ny1 - 2.f * acc[i * 4 + 1];
                o.z = nxi + ny2 - 2.f * acc[i * 4 + 2];
                o.w = nxi + ny3 - 2.f * acc[i * 4 + 3];
                *(float4*)&dist[((size_t)b * NN + n0 + ni + i) * MM + m0 + mi] = o;
            }
        }
        if (blockIdx.x == 0 && tid == 0) lossAcc[0] = 0.f;  // early init, fenced by syncs below
    }
    __threadfence();
    grid.sync();

    // -------- P2: scores = softmax(-dist) per row --------
    {
        float* red = smem;
        for (int r = blockIdx.x; r < BB * NN; r += nblk) {
            const float* dr = dist + (size_t)r * MM;
            float v[3]; float mn = 1e30f;
            for (int q = 0; q < 3; q++) { v[q] = dr[tid + 256 * q]; mn = fminf(mn, v[q]); }
            for (int off = 32; off >= 1; off >>= 1) mn = fminf(mn, __shfl_down(mn, off));
            if (lane == 0) red[wv] = mn;
            __syncthreads();
            mn = fminf(fminf(red[0], red[1]), fminf(red[2], red[3]));
            __syncthreads();
            float e[3], z = 0.f;
            for (int q = 0; q < 3; q++) { e[q] = expf(mn - v[q]); z += e[q]; }
            for (int off = 32; off >= 1; off >>= 1) z += __shfl_down(z, off);
            if (lane == 0) red[wv] = z;
            __syncthreads();
            z = red[0] + red[1] + red[2] + red[3];
            float inv = 1.0f / z;
            for (int q = 0; q < 3; q++) scores[(size_t)r * MM + tid + 256 * q] = e[q] * inv;
            __syncthreads();
        }
    }
    __threadfence();
    grid.sync();

    // -------- P3: consensus + refined softmax + src_corr + rowmax --------
    {
        float* Arow = smem;          // 768
        float* red  = smem + 768;    // 4
        float* red4 = smem + 772;    // 16
        float marg = nn_margin_p[0];
        for (int r = blockIdx.x; r < BB * NN; r += nblk) {
            __syncthreads();
            int b = r / NN, n = r % NN;
            int rows[KK1 - 1];
            for (int j = 0; j < KK1 - 1; j++) rows[j] = src_idx1[r * KK1 + 1 + j];
            for (int q = 0; q < 3; q++) {
                int m = tid + 256 * q;
                float a = 0.f;
                for (int j = 0; j < KK1 - 1; j++) a += scores[(size_t)rows[j] * MM + m];
                Arow[m] = a;
            }
            __syncthreads();
            const float* drow = dist + (size_t)r * MM;
            float rv[3]; float mn = 1e30f;
            for (int q = 0; q < 3; q++) {
                int m = tid + 256 * q;
                const int4* ip = (const int4*)(idx2 + ((size_t)b * MM + m) * KK1);
                int4 i0 = ip[0], i1 = ip[1];
                float cons = Arow[i0.y] + Arow[i0.z] + Arow[i0.w] +
                             Arow[i1.x] + Arow[i1.y] + Arow[i1.z] + Arow[i1.w];
                rv[q] = expf(marg - cons * (1.0f / (KK1 - 1))) * drow[m];
                mn = fminf(mn, rv[q]);
            }
            for (int off = 32; off >= 1; off >>= 1) mn = fminf(mn, __shfl_down(mn, off));
            if (lane == 0) red[wv] = mn;
            __syncthreads();
            mn = fminf(fminf(red[0], red[1]), fminf(red[2], red[3]));
            float z = 0.f, s0 = 0.f, s1 = 0.f, s2 = 0.f;
            const float* t0 = tgt + (size_t)b * 3 * MM;
            for (int q = 0; q < 3; q++) {
                int m = tid + 256 * q;
                float e = expf(mn - rv[q]);
                z += e;
                s0 += e * t0[m];
                s1 += e * t0[MM + m];
                s2 += e * t0[2 * MM + m];
            }
            for (int off = 32; off >= 1; off >>= 1) {
                z += __shfl_down(z, off); s0 += __shfl_down(s0, off);
                s1 += __shfl_down(s1, off); s2 += __shfl_down(s2, off);
            }
            if (lane == 0) { red4[wv*4] = z; red4[wv*4+1] = s0; red4[wv*4+2] = s1; red4[wv*4+3] = s2; }
            __syncthreads();
            if (tid == 0) {
                float zt  = red4[0] + red4[4] + red4[8]  + red4[12];
                float s0t = red4[1] + red4[5] + red4[9]  + red4[13];
                float s1t = red4[2] + red4[6] + red4[10] + red4[14];
                float s2t = red4[3] + red4[7] + red4[11] + red4[15];
                float inv = 1.0f / zt;
                src_corr[(size_t)(b * 3 + 0) * NN + n] = s0t * inv;
                src_corr[(size_t)(b * 3 + 1) * NN + n] = s1t * inv;
                src_corr[(size_t)(b * 3 + 2) * NN + n] = s2t * inv;
                mmax[r] = inv;
            }
        }
    }
    __threadfence();
    grid.sync();

    // -------- P4: knn distances + discriminator MLP -> wgt --------
    {
        float* w1s = smem;                  // 448  (stride 7)
        float* w2s = smem + 448;            // 4160 (stride 65)
        float* w3s = smem + 4608;           // 2080 (stride 65)
        float* xs  = smem + 6688;           // 4*96
        float* h1s = smem + 7072;           // 4*1024
        float* gs  = smem + 11168;          // 4*64
        for (int i = tid; i < 64 * 6; i += 256) w1s[(i / 6) * 7 + (i % 6)] = w1[i];
        for (int i = tid; i < 64 * 64; i += 256) w2s[(i / 64) * 65 + (i % 64)] = w2[i];
        for (int i = tid; i < 32 * 64; i += 256) w3s[(i / 64) * 65 + (i % 64)] = w3[i];
        int w = wv, l = lane;
        for (int job = blockIdx.x; job < BB * NN / 4; job += nblk) {
            __syncthreads();
            int r = job * 4 + w;
            int b = r / NN, n = r % NN;
            if (l < KK) {
                int j = l;
                int f = src_idx[r * KK + j];
                int fb = f / NN, fn = f % NN;
                for (int c = 0; c < 3; c++) {
                    float scn = src_corr[(size_t)(b * 3 + c) * NN + n];
                    float kd = scn - src_corr[(size_t)(fb * 3 + c) * NN + fn];
                    xs[w * 96 + j * 6 + c] = kd;
                    knnD[((size_t)r * KK + j) * 3 + c] = kd;
                    float sd = src[(size_t)(b * 3 + c) * NN + n] - src_knn[((size_t)r * KK + j) * 3 + c];
                    xs[w * 96 + j * 6 + 3 + c] = sd;
                }
            }
            __syncthreads();
            float bb1 = b1[l];
            for (int k = 0; k < KK; k++) {
                float h = bb1;
                for (int c = 0; c < 6; c++) h += xs[w * 96 + k * 6 + c] * w1s[l * 7 + c];
                h1s[w * 1024 + k * 64 + l] = h > 0.f ? h : 0.f;
            }
            __syncthreads();
            float bb2 = b2[l];
            float acc2[KK];
            for (int k = 0; k < KK; k++) acc2[k] = bb2;
            for (int o4 = 0; o4 < 16; o4++) {
                float wa = w2s[l * 65 + o4 * 4 + 0];
                float wb = w2s[l * 65 + o4 * 4 + 1];
                float wc = w2s[l * 65 + o4 * 4 + 2];
                float wd = w2s[l * 65 + o4 * 4 + 3];
                for (int k = 0; k < KK; k++) {
                    float4 h = *(const float4*)&h1s[w * 1024 + k * 64 + o4 * 4];
                    acc2[k] += h.x * wa + h.y * wb + h.z * wc + h.w * wd;
                }
            }
            float gm = 0.f;
            for (int k = 0; k < KK; k++) gm = fmaxf(gm, acc2[k]);
            gs[w * 64 + l] = gm;
            __syncthreads();
            float val = 0.f;
            if (l < 32) {
                float h = b3[l];
                for (int o = 0; o < 64; o++) h += gs[w * 64 + o] * w3s[l * 65 + o];
                h = h > 0.f ? h : 0.f;
                val = h * w4[l];
            }
            for (int off = 32; off >= 1; off >>= 1) val += __shfl_down(val, off);
            if (l == 0) wgt[r] = 1.0f / (1.0f + expf(-(val + b4[0])));
        }
    }
    __threadfence();
    grid.sync();

    // -------- P5: block 0 = moment sums + Horn/Jacobi; blocks 1..48 = topk --------
    if (blockIdx.x == 0) {
        double* redd = (double*)smem_raw;   // 64 doubles
        int b = wv;
        double acc[16];
        for (int k = 0; k < 16; k++) acc[k] = 0.0;
        for (int n = lane; n < NN; n += 64) {
            double wvv = wgt[b * NN + n];
            double s[3], q[3];
            for (int i = 0; i < 3; i++) {
                s[i] = src[(size_t)(b * 3 + i) * NN + n];
                q[i] = src_corr[(size_t)(b * 3 + i) * NN + n];
            }
            acc[0] += wvv;
            for (int i = 0; i < 3; i++) acc[1 + i] += wvv * s[i];
            for (int j = 0; j < 3; j++) acc[4 + j] += wvv * q[j];
            for (int i = 0; i < 3; i++)
                for (int j = 0; j < 3; j++) acc[7 + i * 3 + j] += wvv * s[i] * q[j];
        }
        for (int k = 0; k < 16; k++)
            for (int off = 32; off >= 1; off >>= 1) acc[k] += __shfl_down(acc[k], off);
        if (lane == 0)
            for (int k = 0; k < 16; k++) redd[b * 16 + k] = acc[k];
        __syncthreads();
        if (tid < BB) {
            int bb = tid;
            const double* S = redd + bb * 16;
            double T = S[0], D = T + 1e-8;
            double sm[3], cm[3];
            for (int i = 0; i < 3; i++) { sm[i] = S[1 + i] / D; cm[i] = S[4 + i] / D; }
            double fac = 2.0 - T / D;
            double H[3][3];
            for (int i = 0; i < 3; i++)
                for (int j = 0; j < 3; j++) H[i][j] = S[7 + i * 3 + j] / D - sm[i] * cm[j] * fac;
            double Sxx = H[0][0], Sxy = H[0][1], Sxz = H[0][2];
            double Syx = H[1][0], Syy = H[1][1], Syz = H[1][2];
            double Szx = H[2][0], Szy = H[2][1], Szz = H[2][2];
            double A[4][4];
            A[0][0] = Sxx + Syy + Szz; A[0][1] = Syz - Szy;        A[0][2] = Szx - Sxz;        A[0][3] = Sxy - Syx;
            A[1][0] = A[0][1];         A[1][1] = Sxx - Syy - Szz;  A[1][2] = Sxy + Syx;        A[1][3] = Szx + Sxz;
            A[2][0] = A[0][2];         A[2][1] = A[1][2];          A[2][2] = -Sxx + Syy - Szz; A[2][3] = Syz + Szy;
            A[3][0] = A[0][3];         A[3][1] = A[1][3];          A[3][2] = A[2][3];          A[3][3] = -Sxx - Syy + Szz;
            double V[4][4] = {{1,0,0,0},{0,1,0,0},{0,0,1,0},{0,0,0,1}};
            for (int sweep = 0; sweep < 15; sweep++) {
                double offd = A[0][1]*A[0][1] + A[0][2]*A[0][2] + A[0][3]*A[0][3]
                            + A[1][2]*A[1][2] + A[1][3]*A[1][3] + A[2][3]*A[2][3];
                if (offd < 1e-26) break;
                for (int p = 0; p < 3; p++) {
                    for (int q = p + 1; q < 4; q++) {
                        double apq = A[p][q];
                        if (fabs(apq) < 1e-60) continue;
                        double theta = 0.5 * (A[q][q] - A[p][p]) / apq;
                        double t = (theta >= 0 ? 1.0 : -1.0) / (fabs(theta) + sqrt(theta * theta + 1.0));
                        double c = 1.0 / sqrt(t * t + 1.0), s = t * c;
                        for (int k = 0; k < 4; k++) {
                            double akp = A[k][p], akq = A[k][q];
                            A[k][p] = c * akp - s * akq; A[k][q] = s * akp + c * akq;
                        }
                        for (int k = 0; k < 4; k++) {
                            double apk = A[p][k], aqk = A[q][k];
                            A[p][k] = c * apk - s * aqk; A[q][k] = s * apk + c * aqk;
                        }
                        for (int k = 0; k < 4; k++) {
                            double vkp = V[k][p], vkq = V[k][q];
                            V[k][p] = c * vkp - s * vkq; V[k][q] = s * vkp + c * vkq;
                        }
                    }
                }
            }
            int best = 0;
            for (int k = 1; k < 4; k++) if (A[k][k] > A[best][best]) best = k;
            double qw = V[0][best], qx = V[1][best], qy = V[2][best], qz = V[3][best];
            double nq = sqrt(qw * qw + qx * qx + qy * qy + qz * qz);
            qw /= nq; qx /= nq; qy /= nq; qz /= nq;
            double R[3][3];
            R[0][0] = 1 - 2 * (qy * qy + qz * qz); R[0][1] = 2 * (qx * qy - qw * qz); R[0][2] = 2 * (qx * qz + qw * qy);
            R[1][0] = 2 * (qx * qy + qw * qz); R[1][1] = 1 - 2 * (qx * qx + qz * qz); R[1][2] = 2 * (qy * qz - qw * qx);
            R[2][0] = 2 * (qx * qz - qw * qy); R[2][1] = 2 * (qy * qz + qw * qx); R[2][2] = 1 - 2 * (qx * qx + qy * qy);
            for (int i = 0; i < 3; i++)
                for (int j = 0; j < 3; j++) {
                    out[OFF_R + bb * 9 + i * 3 + j] = (float)R[i][j];
                    Rws[bb * 9 + i * 3 + j] = (float)R[i][j];
                }
            for (int i = 0; i < 3; i++) {
                double tv = cm[i] - (R[i][0] * sm[0] + R[i][1] * sm[1] + R[i][2] * sm[2]);
                out[OFF_T + bb * 3 + i] = (float)tv;
                tws[bb * 3 + i] = (float)tv;
            }
        }
    } else if (blockIdx.x <= 48) {
        int job = blockIdx.x - 1;
        int bx = job % 12, b = job / 12;
        float* wl = smem;  // 768
        for (int i = tid; i < NN; i += 256) wl[i] = wgt[b * NN + i];
        __syncthreads();
        int i = bx * 64 + (tid >> 2);
        int q = tid & 3;
        float v = wl[i];
        int rank = 0;
        for (int t = 0; t < NN / 4; t++) {
            int j = q + 4 * t;
            float u = wl[j];
            rank += (u > v) || (u == v && j < i);
        }
        rank += __shfl_down(rank, 2, 4);
        rank += __shfl_down(rank, 1, 4);
        if (q == 0 && rank < NKP) topk[b * NKP + rank] = i;
    }
    __threadfence();
    grid.sync();

    // -------- P6: gathers (st inline) + loss accumulation --------
    if (blockIdx.x < 64) {
        float* lred = smem;
        int t = blockIdx.x * 256 + tid;
        int j = t % KK; int br = t / KK; int r = br % NKP; int b = br / NKP;
        int idx = topk[b * NKP + r];
        int rr = b * NN + idx;
        for (int c = 0; c < 3; c++)
            out[OFF_TKK + (size_t)((b * 3 + c) * NKP + r) * KK + j] = knnD[((size_t)rr * KK + j) * 3 + c];
        int f = src_idx[rr * KK + j];
        int fb = f / NN, fn = f % NN;
        float Rb[9], tb[3], Rf[9], tf[3];
        for (int c = 0; c < 9; c++) { Rb[c] = Rws[b * 9 + c]; Rf[c] = Rws[fb * 9 + c]; }
        for (int c = 0; c < 3; c++) { tb[c] = tws[b * 3 + c]; tf[c] = tws[fb * 3 + c]; }
        float sp[3], sf[3];
        for (int c = 0; c < 3; c++) {
            sp[c] = src[(size_t)(b * 3 + c) * NN + idx];
            sf[c] = src[(size_t)(fb * 3 + c) * NN + fn];
        }
        for (int c = 0; c < 3; c++) {
            float sti = Rb[c*3] * sp[0] + Rb[c*3+1] * sp[1] + Rb[c*3+2] * sp[2] + tb[c];
            float stf = Rf[c*3] * sf[0] + Rf[c*3+1] * sf[1] + Rf[c*3+2] * sf[2] + tf[c];
            out[OFF_SKK + (size_t)((b * 3 + c) * NKP + r) * KK + j] = sti - stf;
        }
        float term = 0.f;
        if (j == 0) {
            for (int c = 0; c < 3; c++) {
                out[OFF_SK + (b * 3 + c) * NKP + r] = sp[c];
                out[OFF_TK + (b * 3 + c) * NKP + r] = src_corr[(size_t)(b * 3 + c) * NN + idx];
            }
            term = -logf(mmax[rr] + 1e-15f);
        }
        for (int off = 32; off >= 1; off >>= 1) term += __shfl_down(term, off);
        if (lane == 0) lred[wv] = term;
        __syncthreads();
        if (tid == 0) atomicAdd(&lossAcc[0], lred[0] + lred[1] + lred[2] + lred[3]);
    }
    __threadfence();
    grid.sync();
    if (blockIdx.x == 0 && tid == 0) out[OFF_LOSS] = lossAcc[0] * (1.0f / (BB * NKP));
}

// ============================ FALLBACK (R4 path) ============================
__global__ __launch_bounds__(256) void dist_k(const float* __restrict__ xe,
                                              const float* __restrict__ ye,
                                              float* __restrict__ dist) {
    __shared__ float xt[CC * 64];
    __shared__ float yt[CC * 64];
    __shared__ float nx[64];
    __shared__ float ny[64];
    int b = blockIdx.z, n0 = blockIdx.y * 64, m0 = blockIdx.x * 64;
    int tid = threadIdx.x;
    for (int i = tid; i < CC * 16; i += 256) {
        int c = i >> 4, v = i & 15;
        ((float4*)xt)[c * 16 + v] = ((const float4*)(xe + (size_t)(b * CC + c) * NN + n0))[v];
        ((float4*)yt)[c * 16 + v] = ((const float4*)(ye + (size_t)(b * CC + c) * MM + m0))[v];
    }
    __syncthreads();
    if (tid < 64) {
        float s = 0.f;
        for (int c = 0; c < CC; c++) { float v = xt[c * 64 + tid]; s += v * v; }
        nx[tid] = s;
    } else if (tid < 128) {
        int v0 = tid - 64;
        float s = 0.f;
        for (int c = 0; c < CC; c++) { float v = yt[c * 64 + v0]; s += v * v; }
        ny[v0] = s;
    }
    int mi = (tid & 15) * 4, ni = (tid >> 4) * 4;
    float acc[16];
    for (int k = 0; k < 16; k++) acc[k] = 0.f;
    for (int c = 0; c < CC; c++) {
        float4 xv = *(const float4*)&xt[c * 64 + ni];
        float4 yv = *(const float4*)&yt[c * 64 + mi];
        acc[0]  += xv.x * yv.x; acc[1]  += xv.x * yv.y; acc[2]  += xv.x * yv.z; acc[3]  += xv.x * yv.w;
        acc[4]  += xv.y * yv.x; acc[5]  += xv.y * yv.y; acc[6]  += xv.y * yv.z; acc[7]  += xv.y * yv.w;
        acc[8]  += xv.z * yv.x; acc[9]  += xv.z * yv.y; acc[10] += xv.z * yv.z; acc[11] += xv.z * yv.w;
        acc[12] += xv.w * yv.x; acc[13] += xv.w * yv.y; acc[14] += xv.w * yv.z; acc[15] += xv.w * yv.w;
    }
    __syncthreads();
    float ny0 = ny[mi], ny1 = ny[mi + 1], ny2 = ny[mi + 2], ny3 = ny[mi + 3];
    for (int i = 0; i < 4; i++) {
        float nxi = nx[ni + i];
        float4 o;
        o.x = nxi + ny0 - 2.f * acc[i * 4 + 0];
        o.y = nxi + ny1 - 2.f * acc[i * 4 + 1];
        o.z = nxi + ny2 - 2.f * acc[i * 4 + 2];
        o.w = nxi + ny3 - 2.f * acc[i * 4 + 3];
        *(float4*)&dist[((size_t)b * NN + n0 + ni + i) * MM + m0 + mi] = o;
    }
}

__global__ __launch_bounds__(256) void scores_k(const float* __restrict__ dist,
                                                float* __restrict__ scores) {
    __shared__ float red[4];
    int r = blockIdx.x, tid = threadIdx.x;
    int lane = tid & 63, wv = tid >> 6;
    const float* dr = dist + (size_t)r * MM;
    float v[3]; float mn = 1e30f;
    for (int q = 0; q < 3; q++) { v[q] = dr[tid + 256 * q]; mn = fminf(mn, v[q]); }
    for (int off = 32; off >= 1; off >>= 1) mn = fminf(mn, __shfl_down(mn, off));
    if (lane == 0) red[wv] = mn;
    __syncthreads();
    mn = fminf(fminf(red[0], red[1]), fminf(red[2], red[3]));
    __syncthreads();
    float e[3], z = 0.f;
    for (int q = 0; q < 3; q++) { e[q] = expf(mn - v[q]); z += e[q]; }
    for (int off = 32; off >= 1; off >>= 1) z += __shfl_down(z, off);
    if (lane == 0) red[wv] = z;
    __syncthreads();
    z = red[0] + red[1] + red[2] + red[3];
    float inv = 1.0f / z;
    for (int q = 0; q < 3; q++) scores[(size_t)r * MM + tid + 256 * q] = e[q] * inv;
}

__global__ __launch_bounds__(256) void match_k(const float* __restrict__ dist,
                                               const float* __restrict__ scores,
                                               const int* __restrict__ src_idx1,
                                               const int* __restrict__ idx2,
                                               const float* __restrict__ tgt,
                                               const float* __restrict__ nn_margin_p,
                                               float* __restrict__ src_corr,
                                               float* __restrict__ mmax) {
    __shared__ float Arow[MM];
    __shared__ float red[4];
    __shared__ float red4[16];
    int r = blockIdx.x, tid = threadIdx.x;
    int lane = tid & 63, wv = tid >> 6;
    int b = r / NN, n = r % NN;
    int rows[KK1 - 1];
    for (int j = 0; j < KK1 - 1; j++) rows[j] = src_idx1[r * KK1 + 1 + j];
    for (int q = 0; q < 3; q++) {
        int m = tid + 256 * q;
        float a = 0.f;
        for (int j = 0; j < KK1 - 1; j++) a += scores[(size_t)rows[j] * MM + m];
        Arow[m] = a;
    }
    __syncthreads();
    float marg = nn_margin_p[0];
    const float* drow = dist + (size_t)r * MM;
    float rv[3]; float mn = 1e30f;
    for (int q = 0; q < 3; q++) {
        int m = tid + 256 * q;
        const int4* ip = (const int4*)(idx2 + ((size_t)b * MM + m) * KK1);
        int4 i0 = ip[0], i1 = ip[1];
        float cons = Arow[i0.y] + Arow[i0.z] + Arow[i0.w] +
                     Arow[i1.x] + Arow[i1.y] + Arow[i1.z] + Arow[i1.w];
        rv[q] = expf(marg - cons * (1.0f / (KK1 - 1))) * drow[m];
        mn = fminf(mn, rv[q]);
    }
    for (int off = 32; off >= 1; off >>= 1) mn = fminf(mn, __shfl_down(mn, off));
    if (lane == 0) red[wv] = mn;
    __syncthreads();
    mn = fminf(fminf(red[0], red[1]), fminf(red[2], red[3]));
    float z = 0.f, s0 = 0.f, s1 = 0.f, s2 = 0.f;
    const float* t0 = tgt + (size_t)b * 3 * MM;
    for (int q = 0; q < 3; q++) {
        int m = tid + 256 * q;
        float e = expf(mn - rv[q]);
        z += e;
        s0 += e * t0[m];
        s1 += e * t0[MM + m];
        s2 += e * t0[2 * MM + m];
    }
    for (int off = 32; off >= 1; off >>= 1) {
        z += __shfl_down(z, off); s0 += __shfl_down(s0, off);
        s1 += __shfl_down(s1, off); s2 += __shfl_down(s2, off);
    }
    if (lane == 0) { red4[wv * 4] = z; red4[wv * 4 + 1] = s0; red4[wv * 4 + 2] = s1; red4[wv * 4 + 3] = s2; }
    __syncthreads();
    if (tid == 0) {
        float zt = red4[0] + red4[4] + red4[8] + red4[12];
        float s0t = red4[1] + red4[5] + red4[9] + red4[13];
        float s1t = red4[2] + red4[6] + red4[10] + red4[14];
        float s2t = red4[3] + red4[7] + red4[11] + red4[15];
        float inv = 1.0f / zt;
        src_corr[(size_t)(b * 3 + 0) * NN + n] = s0t * inv;
        src_corr[(size_t)(b * 3 + 1) * NN + n] = s1t * inv;
        src_corr[(size_t)(b * 3 + 2) * NN + n] = s2t * inv;
        mmax[r] = inv;
    }
}

__global__ __launch_bounds__(256) void disc_k(const float* __restrict__ src,
                                              const float* __restrict__ src_corr,
                                              const float* __restrict__ src_knn,
                                              const int* __restrict__ src_idx,
                                              const float* __restrict__ w1, const float* __restrict__ b1,
                                              const float* __restrict__ w2, const float* __restrict__ b2,
                                              const float* __restrict__ w3, const float* __restrict__ b3,
                                              const float* __restrict__ w4, const float* __restrict__ b4,
                                              float* __restrict__ knnD, float* __restrict__ wgt) {
    __shared__ float w1s[64 * 7];
    __shared__ float w2s[64 * 65];
    __shared__ float w3s[32 * 65];
    __shared__ float xs[4][16 * 6];
    __shared__ float h1s[4][16 * 64];
    __shared__ float gs[4][64];
    int tid = threadIdx.x;
    for (int i = tid; i < 64 * 6; i += 256) w1s[(i / 6) * 7 + (i % 6)] = w1[i];
    for (int i = tid; i < 64 * 64; i += 256) w2s[(i / 64) * 65 + (i % 64)] = w2[i];
    for (int i = tid; i < 32 * 64; i += 256) w3s[(i / 64) * 65 + (i % 64)] = w3[i];
    int w = tid >> 6, l = tid & 63;
    int r = blockIdx.x * 4 + w;
    int b = r / NN, n = r % NN;
    if (l < KK) {
        int j = l;
        int f = src_idx[r * KK + j];
        int fb = f / NN, fn = f % NN;
        for (int c = 0; c < 3; c++) {
            float scn = src_corr[(size_t)(b * 3 + c) * NN + n];
            float kd = scn - src_corr[(size_t)(fb * 3 + c) * NN + fn];
            xs[w][j * 6 + c] = kd;
            knnD[((size_t)r * KK + j) * 3 + c] = kd;
            float sd = src[(size_t)(b * 3 + c) * NN + n] - src_knn[((size_t)r * KK + j) * 3 + c];
            xs[w][j * 6 + 3 + c] = sd;
        }
    }
    __syncthreads();
    float bb1 = b1[l];
    for (int k = 0; k < KK; k++) {
        float h = bb1;
        for (int c = 0; c < 6; c++) h += xs[w][k * 6 + c] * w1s[l * 7 + c];
        h1s[w][k * 64 + l] = h > 0.f ? h : 0.f;
    }
    __syncthreads();
    float bb2 = b2[l];
    float acc2[KK];
    for (int k = 0; k < KK; k++) acc2[k] = bb2;
    for (int o4 = 0; o4 < 16; o4++) {
        float wa = w2s[l * 65 + o4 * 4 + 0];
        float wb = w2s[l * 65 + o4 * 4 + 1];
        float wc = w2s[l * 65 + o4 * 4 + 2];
        float wd = w2s[l * 65 + o4 * 4 + 3];
        for (int k = 0; k < KK; k++) {
            float4 h = *(const float4*)&h1s[w][k * 64 + o4 * 4];
            acc2[k] += h.x * wa + h.y * wb + h.z * wc + h.w * wd;
        }
    }
    float gm = 0.f;
    for (int k = 0; k < KK; k++) gm = fmaxf(gm, acc2[k]);
    gs[w][l] = gm;
    __syncthreads();
    float val = 0.f;
    if (l < 32) {
        float h = b3[l];
        for (int o = 0; o < 64; o++) h += gs[w][o] * w3s[l * 65 + o];
        h = h > 0.f ? h : 0.f;
        val = h * w4[l];
    }
    for (int off = 32; off >= 1; off >>= 1) val += __shfl_down(val, off);
    if (l == 0) wgt[r] = 1.0f / (1.0f + expf(-(val + b4[0])));
}

__global__ __launch_bounds__(256) void bsumrigid_k(const float* __restrict__ src,
                                                   const float* __restrict__ src_corr,
                                                   const float* __restrict__ wgt,
                                                   float* __restrict__ out,
                                                   float* __restrict__ Rws, float* __restrict__ tws,
                                                   float* __restrict__ lossAcc) {
    __shared__ double redd[BB * 16];
    int tid = threadIdx.x;
    int wv = tid >> 6, lane = tid & 63;
    int b = wv;
    double acc[16];
    for (int k = 0; k < 16; k++) acc[k] = 0.0;
    for (int n = lane; n < NN; n += 64) {
        double wvv = wgt[b * NN + n];
        double s[3], q[3];
        for (int i = 0; i < 3; i++) {
            s[i] = src[(size_t)(b * 3 + i) * NN + n];
            q[i] = src_corr[(size_t)(b * 3 + i) * NN + n];
        }
        acc[0] += wvv;
        for (int i = 0; i < 3; i++) acc[1 + i] += wvv * s[i];
        for (int j = 0; j < 3; j++) acc[4 + j] += wvv * q[j];
        for (int i = 0; i < 3; i++)
            for (int j = 0; j < 3; j++) acc[7 + i * 3 + j] += wvv * s[i] * q[j];
    }
    for (int k = 0; k < 16; k++)
        for (int off = 32; off >= 1; off >>= 1) acc[k] += __shfl_down(acc[k], off);
    if (lane == 0)
        for (int k = 0; k < 16; k++) redd[b * 16 + k] = acc[k];
    __syncthreads();
    if (tid == 0) { lossAcc[0] = 0.f; ((int*)lossAcc)[1] = 0; }
    if (tid >= BB) return;
    int bb = tid;
    const double* S = redd + bb * 16;
    double T = S[0], D = T + 1e-8;
    double sm[3], cm[3];
    for (int i = 0; i < 3; i++) { sm[i] = S[1 + i] / D; cm[i] = S[4 + i] / D; }
    double fac = 2.0 - T / D;
    double H[3][3];
    for (int i = 0; i < 3; i++)
        for (int j = 0; j < 3; j++) H[i][j] = S[7 + i * 3 + j] / D - sm[i] * cm[j] * fac;
    double Sxx = H[0][0], Sxy = H[0][1], Sxz = H[0][2];
    double Syx = H[1][0], Syy = H[1][1], Syz = H[1][2];
    double Szx = H[2][0], Szy = H[2][1], Szz = H[2][2];
    double A[4][4];
    A[0][0] = Sxx + Syy + Szz; A[0][1] = Syz - Szy;        A[0][2] = Szx - Sxz;        A[0][3] = Sxy - Syx;
    A[1][0] = A[0][1];         A[1][1] = Sxx - Syy - Szz;  A[1][2] = Sxy + Syx;        A[1][3] = Szx + Sxz;
    A[2][0] = A[0][2];         A[2][1] = A[1][2];          A[2][2] = -Sxx + Syy - Szz; A[2][3] = Syz + Szy;
    A[3][0] = A[0][3];         A[3][1] = A[1][3];          A[3][2] = A[2][3];          A[3][3] = -Sxx - Syy + Szz;
    double V[4][4] = {{1,0,0,0},{0,1,0,0},{0,0,1,0},{0,0,0,1}};
    for (int sweep = 0; sweep < 15; sweep++) {
        double offd = A[0][1]*A[0][1] + A[0][2]*A[0][2] + A[0][3]*A[0][3]
                    + A[1][2]*A[1][2] + A[1][3]*A[1][3] + A[2][3]*A[2][3];
        if (offd < 1e-26) break;
        for (int p = 0; p < 3; p++) {
            for (int q = p + 1; q < 4; q++) {
                double apq = A[p][q];
                if (fabs(apq) < 1e-60) continue;
                double theta = 0.5 * (A[q][q] - A[p][p]) / apq;
                double t = (theta >= 0 ? 1.0 : -1.0) / (fabs(theta) + sqrt(theta * theta + 1.0));
                double c = 1.0 / sqrt(t * t + 1.0), s = t * c;
                for (int k = 0; k < 4; k++) {
                    double akp = A[k][p], akq = A[k][q];
                    A[k][p] = c * akp - s * akq; A[k][q] = s * akp + c * akq;
                }
                for (int k = 0; k < 4; k++) {
                    double apk = A[p][k], aqk = A[q][k];
                    A[p][k] = c * apk - s * aqk; A[q][k] = s * apk + c * aqk;
                }
                for (int k = 0; k < 4; k++) {
                    double vkp = V[k][p], vkq = V[k][q];
                    V[k][p] = c * vkp - s * vkq; V[k][q] = s * vkp + c * vkq;
                }
            }
        }
    }
    int best = 0;
    for (int k = 1; k < 4; k++) if (A[k][k] > A[best][best]) best = k;
    double qw = V[0][best], qx = V[1][best], qy = V[2][best], qz = V[3][best];
    double nq = sqrt(qw * qw + qx * qx + qy * qy + qz * qz);
    qw /= nq; qx /= nq; qy /= nq; qz /= nq;
    double R[3][3];
    R[0][0] = 1 - 2 * (qy * qy + qz * qz); R[0][1] = 2 * (qx * qy - qw * qz); R[0][2] = 2 * (qx * qz + qw * qy);
    R[1][0] = 2 * (qx * qy + qw * qz); R[1][1] = 1 - 2 * (qx * qx + qz * qz); R[1][2] = 2 * (qy * qz - qw * qx);
    R[2][0] = 2 * (qx * qz - qw * qy); R[2][1] = 2 * (qy * qz + qw * qx); R[2][2] = 1 - 2 * (qx * qx + qy * qy);
    for (int i = 0; i < 3; i++)
        for (int j = 0; j < 3; j++) {
            out[OFF_R + bb * 9 + i * 3 + j] = (float)R[i][j];
            Rws[bb * 9 + i * 3 + j] = (float)R[i][j];
        }
    for (int i = 0; i < 3; i++) {
        double tv = cm[i] - (R[i][0] * sm[0] + R[i][1] * sm[1] + R[i][2] * sm[2]);
        out[OFF_T + bb * 3 + i] = (float)tv;
        tws[bb * 3 + i] = (float)tv;
    }
}

__global__ __launch_bounds__(256) void topk_k(const float* __restrict__ wgt, int* __restrict__ topk,
                                              const float* __restrict__ src, const float* __restrict__ Rws,
                                              const float* __restrict__ tws, float* __restrict__ st) {
    __shared__ float wl[NN];
    int b = blockIdx.y, tid = threadIdx.x;
    for (int i = tid; i < NN; i += 256) wl[i] = wgt[b * NN + i];
    __syncthreads();
    int i = blockIdx.x * 64 + (tid >> 2);
    int q = tid & 3;
    float v = wl[i];
    int rank = 0;
    for (int t = 0; t < NN / 4; t++) {
        int j = q + 4 * t;
        float u = wl[j];
        rank += (u > v) || (u == v && j < i);
    }
    rank += __shfl_down(rank, 2, 4);
    rank += __shfl_down(rank, 1, 4);
    if (q == 0 && rank < NKP) topk[b * NKP + rank] = i;
    int gid = (b * (NN / 64) + blockIdx.x) * 256 + tid;
    if (gid < BB * 3 * NN) {
        int n = gid % NN; int bi = gid / NN; int b2 = bi / 3, ii = bi % 3;
        const float* Rb = Rws + b2 * 9 + ii * 3;
        const float* sb = src + (size_t)b2 * 3 * NN;
        st[gid] = Rb[0] * sb[n] + Rb[1] * sb[NN + n] + Rb[2] * sb[2 * NN + n] + tws[b2 * 3 + ii];
    }
}

__global__ __launch_bounds__(256) void gather_k(const float* __restrict__ src,
                                                const float* __restrict__ src_corr,
                                                const float* __restrict__ knnD,
                                                const float* __restrict__ st,
                                                const int* __restrict__ src_idx,
                                                const int* __restrict__ topk,
                                                const float* __restrict__ mmax,
                                                float* __restrict__ lossAcc,
                                                float* __restrict__ out) {
    __shared__ float lred[4];
    int tid = threadIdx.x;
    int t = blockIdx.x * 256 + tid;
    int j = t % KK; int br = t / KK; int r = br % NKP; int b = br / NKP;
    int idx = topk[b * NKP + r];
    int rr = b * NN + idx;
    for (int c = 0; c < 3; c++)
        out[OFF_TKK + (size_t)((b * 3 + c) * NKP + r) * KK + j] = knnD[((size_t)rr * KK + j) * 3 + c];
    int f = src_idx[rr * KK + j];
    int fb = f / NN, fn = f % NN;
    for (int c = 0; c < 3; c++)
        out[OFF_SKK + (size_t)((b * 3 + c) * NKP + r) * KK + j] =
            st[(size_t)(b * 3 + c) * NN + idx] - st[(size_t)(fb * 3 + c) * NN + fn];
    float term = 0.f;
    if (j == 0) {
        for (int c = 0; c < 3; c++) {
            out[OFF_SK + (b * 3 + c) * NKP + r] = src[(size_t)(b * 3 + c) * NN + idx];
            out[OFF_TK + (b * 3 + c) * NKP + r] = src_corr[(size_t)(b * 3 + c) * NN + idx];
        }
        term = -logf(mmax[rr] + 1e-15f);
    }
    int lane = tid & 63, wv = tid >> 6;
    for (int off = 32; off >= 1; off >>= 1) term += __shfl_down(term, off);
    if (lane == 0) lred[wv] = term;
    __syncthreads();
    if (tid == 0) {
        float bsum = lred[0] + lred[1] + lred[2] + lred[3];
        atomicAdd(&lossAcc[0], bsum);
        __threadfence();
        int old = atomicAdd((int*)&lossAcc[1], 1);
        if (old == (int)gridDim.x - 1) {
            float fin = atomicAdd(&lossAcc[0], 0.f);
            out[OFF_LOSS] = fin / (float)(BB * NKP);
        }
    }
}

extern "C" void kernel_launch(void* const* d_in, const int* in_sizes, int n_in,
                              void* d_out, int out_size, void* d_ws, size_t ws_size,
                              hipStream_t stream) {
    (void)in_sizes; (void)n_in; (void)out_size; (void)ws_size;
    const float* src      = (const float*)d_in[0];
    const float* tgt      = (const float*)d_in[1];
    const float* se       = (const float*)d_in[2];
    const float* te       = (const float*)d_in[3];
    const int*   src_idx  = (const int*)d_in[4];
    const float* src_knn  = (const float*)d_in[6];
    const int*   src_idx1 = (const int*)d_in[9];
    const int*   idx2     = (const int*)d_in[10];
    const float* w1 = (const float*)d_in[12];
    const float* b1 = (const float*)d_in[13];
    const float* w2 = (const float*)d_in[14];
    const float* b2 = (const float*)d_in[15];
    const float* w3 = (const float*)d_in[16];
    const float* b3 = (const float*)d_in[17];
    const float* w4 = (const float*)d_in[18];
    const float* b4 = (const float*)d_in[19];
    const float* nn_margin = (const float*)d_in[21];
    float* out = (float*)d_out;

    // workspace layout (floats)
    float* ws = (float*)d_ws;
    float* dist     = ws;
    float* scores   = dist + (size_t)BB * NN * MM;
    float* src_corr = scores + (size_t)BB * NN * MM;
    float* mmax     = src_corr + BB * 3 * NN;
    float* knnD     = mmax + BB * NN;
    float* wgt      = knnD + (size_t)BB * NN * KK * 3;
    float* Rws      = wgt + BB * NN;
    float* tws      = Rws + BB * 9;
    float* st       = tws + BB * 3;
    int*   topk     = (int*)(st + BB * 3 * NN);
    float* lossAcc  = (float*)(topk + BB * NKP);

    // cooperative mega-kernel: pick grid from occupancy (deterministic per call)
    int blocksPerCU = 0;
    hipError_t qerr = hipOccupancyMaxActiveBlocksPerMultiprocessor(
        &blocksPerCU, (const void*)mega_k, 256, 0);
    int gridSz = 256;
    if (qerr == hipSuccess && blocksPerCU >= 2) gridSz = 512;
    bool coop_ok = (qerr == hipSuccess && blocksPerCU >= 1);

    if (coop_ok) {
        void* args[] = {
            (void*)&src, (void*)&tgt, (void*)&se, (void*)&te,
            (void*)&src_idx, (void*)&src_knn, (void*)&src_idx1, (void*)&idx2,
            (void*)&w1, (void*)&b1, (void*)&w2, (void*)&b2,
            (void*)&w3, (void*)&b3, (void*)&w4, (void*)&b4,
            (void*)&nn_margin, (void*)&out,
            (void*)&dist, (void*)&scores, (void*)&src_corr, (void*)&mmax,
            (void*)&knnD, (void*)&wgt, (void*)&Rws, (void*)&tws,
            (void*)&topk, (void*)&lossAcc
        };
        hipError_t lerr = hipLaunchCooperativeKernel((const void*)mega_k,
                                                     dim3(gridSz), dim3(256),
                                                     args, 0, stream);
        if (lerr == hipSuccess) return;
    }

    // fallback: proven multi-dispatch path
    dist_k<<<dim3(MM / 64, NN / 64, BB), 256, 0, stream>>>(se, te, dist);
    scores_k<<<BB * NN, 256, 0, stream>>>(dist, scores);
    match_k<<<BB * NN, 256, 0, stream>>>(dist, scores, src_idx1, idx2, tgt, nn_margin,
                                         src_corr, mmax);
    disc_k<<<BB * NN / 4, 256, 0, stream>>>(src, src_corr, src_knn, src_idx,
                                            w1, b1, w2, b2, w3, b3, w4, b4, knnD, wgt);
    bsumrigid_k<<<1, 256, 0, stream>>>(src, src_corr, wgt, out, Rws, tws, lossAcc);
    topk_k<<<dim3(NN / 64, BB), 256, 0, stream>>>(wgt, topk, src, Rws, tws, st);
    gather_k<<<BB * NKP * KK / 256, 256, 0, stream>>>(src, src_corr, knnD, st,
                                                      src_idx, topk, mmax, lossAcc, out);
}

// Round 6
// 184.657 us; speedup vs baseline: 2.9428x; 2.9428x over previous
//
#include <hip/hip_runtime.h>
#include <hip/hip_bf16.h>
#include <math.h>

#define BB 4
#define NN 768
#define MM 768
#define CC 128
#define KK 16
#define KK1 8
#define NKP 256

// output offsets (floats)
#define OFF_R    0
#define OFF_T    36
#define OFF_SK   48
#define OFF_TK   3120
#define OFF_SKK  6192
#define OFF_TKK  55344
#define OFF_LOSS 104496

// ---------------- K1: dist = xx+yy-2*x.y, 64x64 tile, 4x4/thread ----------------
__global__ __launch_bounds__(256) void dist_k(const float* __restrict__ xe,
                                              const float* __restrict__ ye,
                                              float* __restrict__ dist) {
    __shared__ float xt[CC * 64];
    __shared__ float yt[CC * 64];
    __shared__ float nx[64];
    __shared__ float ny[64];
    int b = blockIdx.z, n0 = blockIdx.y * 64, m0 = blockIdx.x * 64;
    int tid = threadIdx.x;
    for (int i = tid; i < CC * 16; i += 256) {
        int c = i >> 4, v = i & 15;
        ((float4*)xt)[c * 16 + v] = ((const float4*)(xe + (size_t)(b * CC + c) * NN + n0))[v];
        ((float4*)yt)[c * 16 + v] = ((const float4*)(ye + (size_t)(b * CC + c) * MM + m0))[v];
    }
    __syncthreads();
    if (tid < 64) {
        float s = 0.f;
        for (int c = 0; c < CC; c++) { float v = xt[c * 64 + tid]; s += v * v; }
        nx[tid] = s;
    } else if (tid < 128) {
        int v0 = tid - 64;
        float s = 0.f;
        for (int c = 0; c < CC; c++) { float v = yt[c * 64 + v0]; s += v * v; }
        ny[v0] = s;
    }
    int mi = (tid & 15) * 4, ni = (tid >> 4) * 4;
    float acc[16];
    for (int k = 0; k < 16; k++) acc[k] = 0.f;
    for (int c = 0; c < CC; c++) {
        float4 xv = *(const float4*)&xt[c * 64 + ni];
        float4 yv = *(const float4*)&yt[c * 64 + mi];
        acc[0]  += xv.x * yv.x; acc[1]  += xv.x * yv.y; acc[2]  += xv.x * yv.z; acc[3]  += xv.x * yv.w;
        acc[4]  += xv.y * yv.x; acc[5]  += xv.y * yv.y; acc[6]  += xv.y * yv.z; acc[7]  += xv.y * yv.w;
        acc[8]  += xv.z * yv.x; acc[9]  += xv.z * yv.y; acc[10] += xv.z * yv.z; acc[11] += xv.z * yv.w;
        acc[12] += xv.w * yv.x; acc[13] += xv.w * yv.y; acc[14] += xv.w * yv.z; acc[15] += xv.w * yv.w;
    }
    __syncthreads();
    float ny0 = ny[mi], ny1 = ny[mi + 1], ny2 = ny[mi + 2], ny3 = ny[mi + 3];
    for (int i = 0; i < 4; i++) {
        float nxi = nx[ni + i];
        float4 o;
        o.x = nxi + ny0 - 2.f * acc[i * 4 + 0];
        o.y = nxi + ny1 - 2.f * acc[i * 4 + 1];
        o.z = nxi + ny2 - 2.f * acc[i * 4 + 2];
        o.w = nxi + ny3 - 2.f * acc[i * 4 + 3];
        *(float4*)&dist[((size_t)b * NN + n0 + ni + i) * MM + m0 + mi] = o;
    }
}

// ---------------- K2: per-row softmax stats (min, 1/Z) — wave per row ----------------
__global__ __launch_bounds__(256) void stats_k(const float* __restrict__ dist,
                                               float* __restrict__ rowstats) {
    int tid = threadIdx.x;
    int lane = tid & 63, wv = tid >> 6;
    int r = blockIdx.x * 4 + wv;
    const float* dr = dist + (size_t)r * MM;
    float4 v4[3];
    float mn = 1e30f;
    for (int q = 0; q < 3; q++) {
        v4[q] = *(const float4*)&dr[256 * q + lane * 4];
        mn = fminf(mn, fminf(fminf(v4[q].x, v4[q].y), fminf(v4[q].z, v4[q].w)));
    }
    for (int off = 32; off >= 1; off >>= 1) mn = fminf(mn, __shfl_down(mn, off));
    mn = __shfl(mn, 0);
    float z = 0.f;
    for (int q = 0; q < 3; q++) {
        z += expf(mn - v4[q].x) + expf(mn - v4[q].y) + expf(mn - v4[q].z) + expf(mn - v4[q].w);
    }
    for (int off = 32; off >= 1; off >>= 1) z += __shfl_down(z, off);
    if (lane == 0) { rowstats[2 * r] = mn; rowstats[2 * r + 1] = 1.0f / z; }
}

// ---------------- K3: consensus + refined softmax + src_corr + rowmax (wave/row) ----
__global__ __launch_bounds__(256) void match_k(const float* __restrict__ dist,
                                               const float* __restrict__ rowstats,
                                               const int* __restrict__ src_idx1,
                                               const int* __restrict__ idx2,
                                               const float* __restrict__ tgt,
                                               const float* __restrict__ nn_margin_p,
                                               float* __restrict__ src_corr,
                                               float* __restrict__ mmax) {
    __shared__ float ArowAll[4 * MM];   // 12 KB, per-wave 768-slice
    int tid = threadIdx.x;
    int lane = tid & 63, wv = tid >> 6;
    int r = blockIdx.x * 4 + wv;
    int b = r / NN, n = r % NN;
    float* Arow = ArowAll + wv * MM;
    int rows[KK1 - 1];
    float mnj[KK1 - 1], izj[KK1 - 1];
    for (int j = 0; j < KK1 - 1; j++) {
        rows[j] = src_idx1[r * KK1 + 1 + j];
        mnj[j] = rowstats[2 * rows[j]];
        izj[j] = rowstats[2 * rows[j] + 1];
    }
    // build A-row from dist directly: scores[j][m] = exp(mn_j - d)*invZ_j
    float4 a4[3];
    for (int q = 0; q < 3; q++) a4[q] = make_float4(0.f, 0.f, 0.f, 0.f);
    for (int j = 0; j < KK1 - 1; j++) {
        const float* dj = dist + (size_t)rows[j] * MM;
        float mj = mnj[j], iz = izj[j];
        for (int q = 0; q < 3; q++) {
            float4 d = *(const float4*)&dj[256 * q + lane * 4];
            a4[q].x += expf(mj - d.x) * iz;
            a4[q].y += expf(mj - d.y) * iz;
            a4[q].z += expf(mj - d.z) * iz;
            a4[q].w += expf(mj - d.w) * iz;
        }
    }
    for (int q = 0; q < 3; q++)
        *(float4*)&Arow[256 * q + lane * 4] = a4[q];
    __syncthreads();   // cross-lane LDS visibility within block
    float marg = nn_margin_p[0];
    const float* drow = dist + (size_t)r * MM;
    float4 rv4[3];
    float mn = 1e30f;
    for (int q = 0; q < 3; q++) {
        int mbase = 256 * q + lane * 4;
        float4 d = *(const float4*)&drow[mbase];
        float rr[4];
        for (int c = 0; c < 4; c++) {
            int m = mbase + c;
            const int4* ip = (const int4*)(idx2 + ((size_t)b * MM + m) * KK1);
            int4 i0 = ip[0], i1 = ip[1];
            float cons = Arow[i0.y] + Arow[i0.z] + Arow[i0.w] +
                         Arow[i1.x] + Arow[i1.y] + Arow[i1.z] + Arow[i1.w];
            float dc = (c == 0) ? d.x : (c == 1) ? d.y : (c == 2) ? d.z : d.w;
            rr[c] = expf(marg - cons * (1.0f / (KK1 - 1))) * dc;
            mn = fminf(mn, rr[c]);
        }
        rv4[q] = make_float4(rr[0], rr[1], rr[2], rr[3]);
    }
    for (int off = 32; off >= 1; off >>= 1) mn = fminf(mn, __shfl_down(mn, off));
    mn = __shfl(mn, 0);
    float z = 0.f, s0 = 0.f, s1 = 0.f, s2 = 0.f;
    const float* t0 = tgt + (size_t)b * 3 * MM;
    for (int q = 0; q < 3; q++) {
        int mbase = 256 * q + lane * 4;
        float4 ta = *(const float4*)&t0[mbase];
        float4 tb = *(const float4*)&t0[MM + mbase];
        float4 tc = *(const float4*)&t0[2 * MM + mbase];
        float4 e4;
        e4.x = expf(mn - rv4[q].x); e4.y = expf(mn - rv4[q].y);
        e4.z = expf(mn - rv4[q].z); e4.w = expf(mn - rv4[q].w);
        z  += e4.x + e4.y + e4.z + e4.w;
        s0 += e4.x * ta.x + e4.y * ta.y + e4.z * ta.z + e4.w * ta.w;
        s1 += e4.x * tb.x + e4.y * tb.y + e4.z * tb.z + e4.w * tb.w;
        s2 += e4.x * tc.x + e4.y * tc.y + e4.z * tc.z + e4.w * tc.w;
    }
    for (int off = 32; off >= 1; off >>= 1) {
        z += __shfl_down(z, off); s0 += __shfl_down(s0, off);
        s1 += __shfl_down(s1, off); s2 += __shfl_down(s2, off);
    }
    if (lane == 0) {
        float inv = 1.0f / z;
        src_corr[(size_t)(b * 3 + 0) * NN + n] = s0 * inv;
        src_corr[(size_t)(b * 3 + 1) * NN + n] = s1 * inv;
        src_corr[(size_t)(b * 3 + 2) * NN + n] = s2 * inv;
        mmax[r] = inv;  // row max of matching = exp(0)/Z
    }
}

// ---------------- K4: knn distances + discriminator MLP -> weight ----------------
__global__ __launch_bounds__(256) void disc_k(const float* __restrict__ src,
                                              const float* __restrict__ src_corr,
                                              const float* __restrict__ src_knn,
                                              const int* __restrict__ src_idx,
                                              const float* __restrict__ w1, const float* __restrict__ b1,
                                              const float* __restrict__ w2, const float* __restrict__ b2,
                                              const float* __restrict__ w3, const float* __restrict__ b3,
                                              const float* __restrict__ w4, const float* __restrict__ b4,
                                              float* __restrict__ knnD, float* __restrict__ wgt) {
    __shared__ float w1s[64 * 7];
    __shared__ float w2s[64 * 65];
    __shared__ float w3s[32 * 65];
    __shared__ float xs[4][16 * 6];
    __shared__ float h1s[4][16 * 64];
    __shared__ float gs[4][64];
    int tid = threadIdx.x;
    for (int i = tid; i < 64 * 6; i += 256) w1s[(i / 6) * 7 + (i % 6)] = w1[i];
    for (int i = tid; i < 64 * 64; i += 256) w2s[(i / 64) * 65 + (i % 64)] = w2[i];
    for (int i = tid; i < 32 * 64; i += 256) w3s[(i / 64) * 65 + (i % 64)] = w3[i];
    int w = tid >> 6, l = tid & 63;
    int r = blockIdx.x * 4 + w;
    int b = r / NN, n = r % NN;
    if (l < KK) {
        int j = l;
        int f = src_idx[r * KK + j];
        int fb = f / NN, fn = f % NN;
        for (int c = 0; c < 3; c++) {
            float scn = src_corr[(size_t)(b * 3 + c) * NN + n];
            float kd = scn - src_corr[(size_t)(fb * 3 + c) * NN + fn];
            xs[w][j * 6 + c] = kd;
            knnD[((size_t)r * KK + j) * 3 + c] = kd;
            float sd = src[(size_t)(b * 3 + c) * NN + n] - src_knn[((size_t)r * KK + j) * 3 + c];
            xs[w][j * 6 + 3 + c] = sd;
        }
    }
    __syncthreads();
    float bb1 = b1[l];
    for (int k = 0; k < KK; k++) {
        float h = bb1;
        for (int c = 0; c < 6; c++) h += xs[w][k * 6 + c] * w1s[l * 7 + c];
        h1s[w][k * 64 + l] = h > 0.f ? h : 0.f;
    }
    __syncthreads();
    float bb2 = b2[l];
    float acc2[KK];
    for (int k = 0; k < KK; k++) acc2[k] = bb2;
    for (int o4 = 0; o4 < 16; o4++) {
        float wa = w2s[l * 65 + o4 * 4 + 0];
        float wb = w2s[l * 65 + o4 * 4 + 1];
        float wc = w2s[l * 65 + o4 * 4 + 2];
        float wd = w2s[l * 65 + o4 * 4 + 3];
        for (int k = 0; k < KK; k++) {
            float4 h = *(const float4*)&h1s[w][k * 64 + o4 * 4];
            acc2[k] += h.x * wa + h.y * wb + h.z * wc + h.w * wd;
        }
    }
    float gm = 0.f;
    for (int k = 0; k < KK; k++) gm = fmaxf(gm, acc2[k]);
    gs[w][l] = gm;
    __syncthreads();
    float val = 0.f;
    if (l < 32) {
        float h = b3[l];
        for (int o = 0; o < 64; o++) h += gs[w][o] * w3s[l * 65 + o];
        h = h > 0.f ? h : 0.f;
        val = h * w4[l];
    }
    for (int off = 32; off >= 1; off >>= 1) val += __shfl_down(val, off);
    if (l == 0) wgt[r] = 1.0f / (1.0f + expf(-(val + b4[0])));
}

// ---------------- K5: blocks 0..47 topk; block 48 moment sums + Horn/Jacobi ---------
__global__ __launch_bounds__(256) void rigidtopk_k(const float* __restrict__ src,
                                                   const float* __restrict__ src_corr,
                                                   const float* __restrict__ wgt,
                                                   float* __restrict__ out,
                                                   float* __restrict__ Rws, float* __restrict__ tws,
                                                   int* __restrict__ topk,
                                                   float* __restrict__ lossAcc) {
    int tid = threadIdx.x;
    int lane = tid & 63, wv = tid >> 6;
    if (blockIdx.x < 48) {
        __shared__ float wl[NN];
        int job = blockIdx.x;
        int bx = job % 12, b = job / 12;
        for (int i = tid; i < NN; i += 256) wl[i] = wgt[b * NN + i];
        __syncthreads();
        int i = bx * 64 + (tid >> 2);
        int q = tid & 3;
        float v = wl[i];
        int rank = 0;
        for (int t = 0; t < NN / 4; t++) {
            int j = q + 4 * t;
            float u = wl[j];
            rank += (u > v) || (u == v && j < i);
        }
        rank += __shfl_down(rank, 2, 4);
        rank += __shfl_down(rank, 1, 4);
        if (q == 0 && rank < NKP) topk[b * NKP + rank] = i;
        return;
    }
    // block 48: per-batch weighted moments (wave per batch) + rigid transform
    __shared__ double redd[BB * 16];
    int b = wv;
    double acc[16];
    for (int k = 0; k < 16; k++) acc[k] = 0.0;
    for (int n = lane; n < NN; n += 64) {
        double wvv = wgt[b * NN + n];
        double s[3], q[3];
        for (int i = 0; i < 3; i++) {
            s[i] = src[(size_t)(b * 3 + i) * NN + n];
            q[i] = src_corr[(size_t)(b * 3 + i) * NN + n];
        }
        acc[0] += wvv;
        for (int i = 0; i < 3; i++) acc[1 + i] += wvv * s[i];
        for (int j = 0; j < 3; j++) acc[4 + j] += wvv * q[j];
        for (int i = 0; i < 3; i++)
            for (int j = 0; j < 3; j++) acc[7 + i * 3 + j] += wvv * s[i] * q[j];
    }
    for (int k = 0; k < 16; k++)
        for (int off = 32; off >= 1; off >>= 1) acc[k] += __shfl_down(acc[k], off);
    if (lane == 0)
        for (int k = 0; k < 16; k++) redd[b * 16 + k] = acc[k];
    __syncthreads();
    if (tid == 0) { lossAcc[0] = 0.f; ((int*)lossAcc)[1] = 0; }
    if (tid >= BB) return;
    int bb = tid;
    const double* S = redd + bb * 16;
    double T = S[0], D = T + 1e-8;
    double sm[3], cm[3];
    for (int i = 0; i < 3; i++) { sm[i] = S[1 + i] / D; cm[i] = S[4 + i] / D; }
    double fac = 2.0 - T / D;
    double H[3][3];
    for (int i = 0; i < 3; i++)
        for (int j = 0; j < 3; j++) H[i][j] = S[7 + i * 3 + j] / D - sm[i] * cm[j] * fac;
    double Sxx = H[0][0], Sxy = H[0][1], Sxz = H[0][2];
    double Syx = H[1][0], Syy = H[1][1], Syz = H[1][2];
    double Szx = H[2][0], Szy = H[2][1], Szz = H[2][2];
    double A[4][4];
    A[0][0] = Sxx + Syy + Szz; A[0][1] = Syz - Szy;        A[0][2] = Szx - Sxz;        A[0][3] = Sxy - Syx;
    A[1][0] = A[0][1];         A[1][1] = Sxx - Syy - Szz;  A[1][2] = Sxy + Syx;        A[1][3] = Szx + Sxz;
    A[2][0] = A[0][2];         A[2][1] = A[1][2];          A[2][2] = -Sxx + Syy - Szz; A[2][3] = Syz + Szy;
    A[3][0] = A[0][3];         A[3][1] = A[1][3];          A[3][2] = A[2][3];          A[3][3] = -Sxx - Syy + Szz;
    double V[4][4] = {{1,0,0,0},{0,1,0,0},{0,0,1,0},{0,0,0,1}};
    for (int sweep = 0; sweep < 15; sweep++) {
        double offd = A[0][1]*A[0][1] + A[0][2]*A[0][2] + A[0][3]*A[0][3]
                    + A[1][2]*A[1][2] + A[1][3]*A[1][3] + A[2][3]*A[2][3];
        if (offd < 1e-26) break;
        for (int p = 0; p < 3; p++) {
            for (int q = p + 1; q < 4; q++) {
                double apq = A[p][q];
                if (fabs(apq) < 1e-60) continue;
                double theta = 0.5 * (A[q][q] - A[p][p]) / apq;
                double t = (theta >= 0 ? 1.0 : -1.0) / (fabs(theta) + sqrt(theta * theta + 1.0));
                double c = 1.0 / sqrt(t * t + 1.0), s = t * c;
                for (int k = 0; k < 4; k++) {
                    double akp = A[k][p], akq = A[k][q];
                    A[k][p] = c * akp - s * akq; A[k][q] = s * akp + c * akq;
                }
                for (int k = 0; k < 4; k++) {
                    double apk = A[p][k], aqk = A[q][k];
                    A[p][k] = c * apk - s * aqk; A[q][k] = s * apk + c * aqk;
                }
                for (int k = 0; k < 4; k++) {
                    double vkp = V[k][p], vkq = V[k][q];
                    V[k][p] = c * vkp - s * vkq; V[k][q] = s * vkp + c * vkq;
                }
            }
        }
    }
    int best = 0;
    for (int k = 1; k < 4; k++) if (A[k][k] > A[best][best]) best = k;
    double qw = V[0][best], qx = V[1][best], qy = V[2][best], qz = V[3][best];
    double nq = sqrt(qw * qw + qx * qx + qy * qy + qz * qz);
    qw /= nq; qx /= nq; qy /= nq; qz /= nq;
    double R[3][3];
    R[0][0] = 1 - 2 * (qy * qy + qz * qz); R[0][1] = 2 * (qx * qy - qw * qz); R[0][2] = 2 * (qx * qz + qw * qy);
    R[1][0] = 2 * (qx * qy + qw * qz); R[1][1] = 1 - 2 * (qx * qx + qz * qz); R[1][2] = 2 * (qy * qz - qw * qx);
    R[2][0] = 2 * (qx * qz - qw * qy); R[2][1] = 2 * (qy * qz + qw * qx); R[2][2] = 1 - 2 * (qx * qx + qy * qy);
    for (int i = 0; i < 3; i++)
        for (int j = 0; j < 3; j++) {
            out[OFF_R + bb * 9 + i * 3 + j] = (float)R[i][j];
            Rws[bb * 9 + i * 3 + j] = (float)R[i][j];
        }
    for (int i = 0; i < 3; i++) {
        double tv = cm[i] - (R[i][0] * sm[0] + R[i][1] * sm[1] + R[i][2] * sm[2]);
        out[OFF_T + bb * 3 + i] = (float)tv;
        tws[bb * 3 + i] = (float)tv;
    }
}

// ---------------- K6: gathers (st inline) + loss (last-block finalize) ----------------
__global__ __launch_bounds__(256) void gather_k(const float* __restrict__ src,
                                                const float* __restrict__ src_corr,
                                                const float* __restrict__ knnD,
                                                const int* __restrict__ src_idx,
                                                const int* __restrict__ topk,
                                                const float* __restrict__ Rws,
                                                const float* __restrict__ tws,
                                                const float* __restrict__ mmax,
                                                float* __restrict__ lossAcc,
                                                float* __restrict__ out) {
    __shared__ float lred[4];
    int tid = threadIdx.x;
    int lane = tid & 63, wv = tid >> 6;
    int t = blockIdx.x * 256 + tid;
    int j = t % KK; int br = t / KK; int r = br % NKP; int b = br / NKP;
    int idx = topk[b * NKP + r];
    int rr = b * NN + idx;
    for (int c = 0; c < 3; c++)
        out[OFF_TKK + (size_t)((b * 3 + c) * NKP + r) * KK + j] = knnD[((size_t)rr * KK + j) * 3 + c];
    int f = src_idx[rr * KK + j];
    int fb = f / NN, fn = f % NN;
    float Rb[9], tb[3], Rf[9], tf[3];
    for (int c = 0; c < 9; c++) { Rb[c] = Rws[b * 9 + c]; Rf[c] = Rws[fb * 9 + c]; }
    for (int c = 0; c < 3; c++) { tb[c] = tws[b * 3 + c]; tf[c] = tws[fb * 3 + c]; }
    float sp[3], sf[3];
    for (int c = 0; c < 3; c++) {
        sp[c] = src[(size_t)(b * 3 + c) * NN + idx];
        sf[c] = src[(size_t)(fb * 3 + c) * NN + fn];
    }
    for (int c = 0; c < 3; c++) {
        float sti = Rb[c*3] * sp[0] + Rb[c*3+1] * sp[1] + Rb[c*3+2] * sp[2] + tb[c];
        float stf = Rf[c*3] * sf[0] + Rf[c*3+1] * sf[1] + Rf[c*3+2] * sf[2] + tf[c];
        out[OFF_SKK + (size_t)((b * 3 + c) * NKP + r) * KK + j] = sti - stf;
    }
    float term = 0.f;
    if (j == 0) {
        for (int c = 0; c < 3; c++) {
            out[OFF_SK + (b * 3 + c) * NKP + r] = sp[c];
            out[OFF_TK + (b * 3 + c) * NKP + r] = src_corr[(size_t)(b * 3 + c) * NN + idx];
        }
        term = -logf(mmax[rr] + 1e-15f);
    }
    for (int off = 32; off >= 1; off >>= 1) term += __shfl_down(term, off);
    if (lane == 0) lred[wv] = term;
    __syncthreads();
    if (tid == 0) {
        float bsum = lred[0] + lred[1] + lred[2] + lred[3];
        atomicAdd(&lossAcc[0], bsum);
        __threadfence();
        int old = atomicAdd((int*)&lossAcc[1], 1);
        if (old == (int)gridDim.x - 1) {
            float fin = atomicAdd(&lossAcc[0], 0.f);
            out[OFF_LOSS] = fin / (float)(BB * NKP);
        }
    }
}

extern "C" void kernel_launch(void* const* d_in, const int* in_sizes, int n_in,
                              void* d_out, int out_size, void* d_ws, size_t ws_size,
                              hipStream_t stream) {
    (void)in_sizes; (void)n_in; (void)out_size; (void)ws_size;
    const float* src      = (const float*)d_in[0];
    const float* tgt      = (const float*)d_in[1];
    const float* se       = (const float*)d_in[2];
    const float* te       = (const float*)d_in[3];
    const int*   src_idx  = (const int*)d_in[4];
    const float* src_knn  = (const float*)d_in[6];
    const int*   src_idx1 = (const int*)d_in[9];
    const int*   idx2     = (const int*)d_in[10];
    const float* w1 = (const float*)d_in[12];
    const float* b1 = (const float*)d_in[13];
    const float* w2 = (const float*)d_in[14];
    const float* b2 = (const float*)d_in[15];
    const float* w3 = (const float*)d_in[16];
    const float* b3 = (const float*)d_in[17];
    const float* w4 = (const float*)d_in[18];
    const float* b4 = (const float*)d_in[19];
    const float* nn_margin = (const float*)d_in[21];
    float* out = (float*)d_out;

    // workspace layout (floats)
    float* ws = (float*)d_ws;
    float* dist     = ws;                                  // 2359296
    float* rowstats = dist + (size_t)BB * NN * MM;         // 6144
    float* src_corr = rowstats + BB * NN * 2;              // 9216
    float* mmax     = src_corr + BB * 3 * NN;              // 3072
    float* knnD     = mmax + BB * NN;                      // 147456
    float* wgt      = knnD + (size_t)BB * NN * KK * 3;     // 3072
    float* Rws      = wgt + BB * NN;                       // 36
    float* tws      = Rws + BB * 9;                        // 12
    int*   topk     = (int*)(tws + BB * 3);                // 1024
    float* lossAcc  = (float*)(topk + BB * NKP);           // 2 (sum, ctr)

    dist_k<<<dim3(MM / 64, NN / 64, BB), 256, 0, stream>>>(se, te, dist);
    stats_k<<<BB * NN / 4, 256, 0, stream>>>(dist, rowstats);
    match_k<<<BB * NN / 4, 256, 0, stream>>>(dist, rowstats, src_idx1, idx2, tgt, nn_margin,
                                             src_corr, mmax);
    disc_k<<<BB * NN / 4, 256, 0, stream>>>(src, src_corr, src_knn, src_idx,
                                            w1, b1, w2, b2, w3, b3, w4, b4, knnD, wgt);
    rigidtopk_k<<<49, 256, 0, stream>>>(src, src_corr, wgt, out, Rws, tws, topk, lossAcc);
    gather_k<<<BB * NKP * KK / 256, 256, 0, stream>>>(src, src_corr, knnD, src_idx, topk,
                                                      Rws, tws, mmax, lossAcc, out);
}